// Round 3
// baseline (106.532 us; speedup 1.0000x reference)
//
#include <hip/hip_runtime.h>
#include <stdint.h>

typedef unsigned long long u64;
typedef __attribute__((ext_vector_type(8))) short short8;   // 8 x bf16 (4 VGPR)
typedef __attribute__((ext_vector_type(4))) float f32x4;    // MFMA C/D frag

#define B_ 32
#define N_ 512
#define FIN_ 80
#define FH_ 50
#define NH_ 3
#define FO_ 80
#define CAT_ 150

__device__ inline unsigned short f2bf(float f) {  // RNE float -> bf16 bits
  unsigned u = __float_as_uint(f);
  u += 0x7fffu + ((u >> 16) & 1u);
  return (unsigned short)(u >> 16);
}

__device__ inline void fma4(float4& a, float s, const float4& w) {
  a.x += s * w.x; a.y += s * w.y; a.z += s * w.z; a.w += s * w.w;
}

// ---------- K1: Wh = h @ Ws[h]; emit e1h/e2h (f32) + whT (bf16 [col64][j512], col63=1)
__global__ __launch_bounds__(256) void k1_prep(const float* __restrict__ h,
                                               const float* __restrict__ Ws,
                                               const float* __restrict__ attn_a,
                                               unsigned short* __restrict__ whT,
                                               float* __restrict__ e1h,
                                               float* __restrict__ e2h) {
  __shared__ __align__(16) float hs[64 * FIN_];   // reused as 64x64 transpose buffer
  __shared__ __align__(16) float ws[FIN_ * 64];
  __shared__ __align__(16) float a1s[64];
  __shared__ __align__(16) float a2s[64];
  int x = blockIdx.x;
  const int rt = x & 7; x >>= 3;
  const int bb = x & 31; x >>= 5;
  const int hh = x;  // 0..2
  const int n0 = rt * 64;
  const int t = threadIdx.x;

  {
    const float4* src = (const float4*)(h + ((size_t)bb * N_ + n0) * FIN_);
    float4* dst = (float4*)hs;
    for (int i = t; i < 64 * FIN_ / 4; i += 256) dst[i] = src[i];
  }
  {
    const float* src = Ws + (size_t)hh * FIN_ * FH_;
    for (int i = t; i < FIN_ * 64; i += 256) {
      int k = i >> 6, c = i & 63;
      ws[i] = (c < FH_) ? src[k * FH_ + c] : 0.0f;
    }
  }
  if (t < 64) {
    a1s[t] = (t < FH_) ? attn_a[hh * 2 * FH_ + t] : 0.0f;
    a2s[t] = (t < FH_) ? attn_a[hh * 2 * FH_ + FH_ + t] : 0.0f;
  }
  __syncthreads();

  const int r = t >> 2, cq = t & 3;
  float4 acc[4];
  for (int i = 0; i < 4; ++i) acc[i] = make_float4(0.f, 0.f, 0.f, 0.f);
  const float4* ws4 = (const float4*)ws;
  #pragma unroll 4
  for (int k = 0; k < FIN_; ++k) {
    float hv = hs[r * FIN_ + k];
    #pragma unroll
    for (int i = 0; i < 4; ++i) fma4(acc[i], hv, ws4[k * 16 + cq * 4 + i]);
  }
  {
    const float4* a14 = (const float4*)a1s;
    const float4* a24 = (const float4*)a2s;
    float p1 = 0.f, p2 = 0.f;
    #pragma unroll
    for (int i = 0; i < 4; ++i) {
      float4 a1 = a14[cq * 4 + i], a2 = a24[cq * 4 + i], v = acc[i];
      p1 += v.x * a1.x + v.y * a1.y + v.z * a1.z + v.w * a1.w;
      p2 += v.x * a2.x + v.y * a2.y + v.z * a2.z + v.w * a2.w;
    }
    p1 += __shfl_xor(p1, 1); p1 += __shfl_xor(p1, 2);
    p2 += __shfl_xor(p2, 1); p2 += __shfl_xor(p2, 2);
    if (cq == 0) {
      size_t o = ((size_t)hh * B_ + bb) * N_ + n0 + r;
      e1h[o] = p1; e2h[o] = p2;
    }
  }
  __syncthreads();
  float* tb = hs;  // tb[j][col], 64x64
  {
    float4* trow = (float4*)(tb + r * 64);
    #pragma unroll
    for (int i = 0; i < 4; ++i) trow[cq * 4 + i] = acc[i];
  }
  __syncthreads();
  for (int g = t; g < 512; g += 256) {
    const int col = g >> 3, jg = g & 7;
    unsigned short pk[8];
    #pragma unroll
    for (int e = 0; e < 8; ++e)
      pk[e] = (col == 63) ? (unsigned short)0x3f80 : f2bf(tb[(jg * 8 + e) * 64 + col]);
    uint4 o;
    o.x = (unsigned)pk[0] | ((unsigned)pk[1] << 16);
    o.y = (unsigned)pk[2] | ((unsigned)pk[3] << 16);
    o.z = (unsigned)pk[4] | ((unsigned)pk[5] << 16);
    o.w = (unsigned)pk[6] | ((unsigned)pk[7] << 16);
    *(uint4*)&whT[(((size_t)hh * B_ + bb) * 64 + col) * 512 + n0 + jg * 8] = o;
  }
}

// ---------- K2: adj -> bitmask ----------------------------------------------------
__global__ __launch_bounds__(256) void k2_mask(const int* __restrict__ adj,
                                               u64* __restrict__ maskw) {
  const int t = threadIdx.x;
  const int w = t >> 6, l = t & 63;
  const int row = blockIdx.x * 4 + w;
  const int* src = adj + (size_t)row * N_;
  u64* dst = maskw + (size_t)row * 8;
  #pragma unroll
  for (int it = 0; it < 8; ++it) {
    int v = src[it * 64 + l];
    u64 m = __ballot(v != 0);
    if (l == 0) dst[it] = m;
  }
}

// A-fragment builder: p = exp(min(lrelu(e1+e2),60)) masked, bf16 -------------------
__device__ inline short8 build_af(const float* e2s, float e1r, u64 word,
                                  int jb, int shift, float& dummy) {
  short8 af;
  unsigned b0 = (unsigned)(word >> shift) & 0xffu;
  float4 va = *(const float4*)&e2s[jb];
  float4 vb = *(const float4*)&e2s[jb + 4];
  float ev[8] = {va.x, va.y, va.z, va.w, vb.x, vb.y, vb.z, vb.w};
  #pragma unroll
  for (int e = 0; e < 8; ++e) {
    float sv = e1r + ev[e];
    sv = fmaxf(sv, 0.2f * sv);
    sv = fminf(sv, 60.f);
    float arg = ((b0 >> e) & 1u) ? sv : -1e30f;
    af[e] = (short)f2bf(__expf(arg));
  }
  return af;
}

// ---------- K3: layer-1 attention. 4 waves x 16 rows, full j; denom via col 63 ----
__global__ __launch_bounds__(256) void k3_attn1(const unsigned short* __restrict__ whT,
                                                const float* __restrict__ e1,
                                                const float* __restrict__ e2,
                                                const u64* __restrict__ maskw,
                                                float* __restrict__ cat) {
  __shared__ __align__(16) float e2s[N_];
  int x = (int)((blockIdx.x & 7) * 96 + (blockIdx.x >> 3));  // XCD-bijective
  const int rt = x & 7; x >>= 3;
  const int bb = x & 31; x >>= 5;
  const int hh = x;
  const int n0 = rt * 64;
  const int t = threadIdx.x;
  const int l = t & 63, wid = t >> 6;
  const int q = l >> 4, rl = l & 15;

  const float* e2p = e2 + ((size_t)hh * B_ + bb) * N_;
  for (int i = t; i < N_ / 4; i += 256) ((float4*)e2s)[i] = ((const float4*)e2p)[i];
  __syncthreads();

  const int row = n0 + wid * 16 + rl;
  const float e1r = e1[((size_t)hh * B_ + bb) * N_ + row];
  const u64* mr = maskw + ((size_t)bb * N_ + row) * 8;

  f32x4 acc[4];
  #pragma unroll
  for (int c = 0; c < 4; ++c) acc[c] = (f32x4){0.f, 0.f, 0.f, 0.f};
  const unsigned short* wb = whT + ((size_t)hh * B_ + bb) * 64 * 512;
  float dummy;

  for (int tt = 0; tt < 8; ++tt) {
    short8 bf[4][2];
    #pragma unroll
    for (int c = 0; c < 4; ++c) {
      const unsigned short* bp = wb + (size_t)(c * 16 + rl) * 512 + tt * 64 + q * 8;
      bf[c][0] = *(const short8*)bp;
      bf[c][1] = *(const short8*)(bp + 32);
    }
    u64 word = mr[tt];
    short8 af0 = build_af(e2s, e1r, word, tt * 64 + q * 8, q * 8, dummy);
    short8 af1 = build_af(e2s, e1r, word, tt * 64 + 32 + q * 8, 32 + q * 8, dummy);
    #pragma unroll
    for (int c = 0; c < 4; ++c) {
      acc[c] = __builtin_amdgcn_mfma_f32_16x16x32_bf16(af0, bf[c][0], acc[c], 0, 0, 0);
      acc[c] = __builtin_amdgcn_mfma_f32_16x16x32_bf16(af1, bf[c][1], acc[c], 0, 0, 0);
    }
  }

  // denom: acc[3] col 63 lives in lane (q<<4)|15, reg r
  const size_t orow0 = (size_t)bb * N_ + n0 + wid * 16;
  #pragma unroll
  for (int r = 0; r < 4; ++r) {
    float srow = __shfl(acc[3][r], (q << 4) | 15);
    float invr = srow > 0.f ? 1.f / srow : 0.f;
    const size_t ob = (orow0 + q * 4 + r) * CAT_ + hh * FH_;
    #pragma unroll
    for (int c = 0; c < 4; ++c) {
      const int col = c * 16 + rl;
      if (col < FH_) {
        float v = acc[c][r] * invr;
        v = v > 0.f ? v : __expf(v) - 1.f;  // ELU
        cat[ob + col] = v;
      }
    }
  }
}

// ---------- K4: Wh2 = cat @ W_out (f32) + e1o/e2o + wh2T bf16 [96][512] -----------
__global__ __launch_bounds__(256) void k4_gemm2(const float* __restrict__ cat,
                                                const float* __restrict__ Wout,
                                                const float* __restrict__ a_out,
                                                unsigned short* __restrict__ wh2T,
                                                float* __restrict__ e1o,
                                                float* __restrict__ e2o) {
  __shared__ __align__(16) float wl[CAT_ * FO_];
  __shared__ __align__(16) float tb[64 * FO_];
  const int t = threadIdx.x;
  {
    const float4* src = (const float4*)Wout;
    float4* dst = (float4*)wl;
    for (int i = t; i < CAT_ * FO_ / 4; i += 256) dst[i] = src[i];
  }
  __syncthreads();
  const int r = t >> 2, cq = t & 3;
  const size_t row = (size_t)blockIdx.x * 64 + r;
  const float* cp = cat + row * CAT_;
  float4 acc[5];
  for (int i = 0; i < 5; ++i) acc[i] = make_float4(0, 0, 0, 0);
  const float4* wl4 = (const float4*)wl;
  #pragma unroll 2
  for (int k = 0; k < CAT_; ++k) {
    float cv = cp[k];
    #pragma unroll
    for (int i = 0; i < 5; ++i) fma4(acc[i], cv, wl4[k * 20 + cq * 5 + i]);
  }
  {
    const float4* a1 = (const float4*)a_out;
    const float4* a2 = (const float4*)(a_out + FO_);
    float p1 = 0.f, p2 = 0.f;
    #pragma unroll
    for (int i = 0; i < 5; ++i) {
      float4 v = acc[i];
      float4 xx = a1[cq * 5 + i], yy = a2[cq * 5 + i];
      p1 += v.x * xx.x + v.y * xx.y + v.z * xx.z + v.w * xx.w;
      p2 += v.x * yy.x + v.y * yy.y + v.z * yy.z + v.w * yy.w;
    }
    p1 += __shfl_xor(p1, 1); p1 += __shfl_xor(p1, 2);
    p2 += __shfl_xor(p2, 1); p2 += __shfl_xor(p2, 2);
    if (cq == 0) { e1o[row] = p1; e2o[row] = p2; }
  }
  {
    float4* trow = (float4*)(tb + r * FO_);
    #pragma unroll
    for (int i = 0; i < 5; ++i) trow[cq * 5 + i] = acc[i];
  }
  __syncthreads();
  const int bb2 = blockIdx.x >> 3, jt = blockIdx.x & 7;
  // 96-col padded layout: cols 80-94 zero, col 95 = 1.0 (softmax denominator)
  for (int g = t; g < 768; g += 256) {
    const int col = g >> 3, jg = g & 7;
    uint4 o;
    if (col < FO_) {
      unsigned short pk[8];
      #pragma unroll
      for (int e = 0; e < 8; ++e) pk[e] = f2bf(tb[(jg * 8 + e) * FO_ + col]);
      o.x = (unsigned)pk[0] | ((unsigned)pk[1] << 16);
      o.y = (unsigned)pk[2] | ((unsigned)pk[3] << 16);
      o.z = (unsigned)pk[4] | ((unsigned)pk[5] << 16);
      o.w = (unsigned)pk[6] | ((unsigned)pk[7] << 16);
    } else {
      unsigned fill = (col == 95) ? 0x3f803f80u : 0u;
      o.x = o.y = o.z = o.w = fill;
    }
    *(uint4*)&wh2T[((size_t)bb2 * 96 + col) * 512 + jt * 64 + jg * 8] = o;
  }
}

// ---------- K5: layer-2 attention, j-split. 16 rows/block, 4 waves over j ---------
__global__ __launch_bounds__(256) void k5_attn2(const unsigned short* __restrict__ wh2T,
                                                const float* __restrict__ e1,
                                                const float* __restrict__ e2,
                                                const u64* __restrict__ maskw,
                                                float* __restrict__ out) {
  __shared__ __align__(16) float e2s[N_];
  __shared__ __align__(16) float red[4][64][25];  // stride 25: conflict-free
  int x = (int)((blockIdx.x & 7) * 128 + (blockIdx.x >> 3));  // XCD-bijective
  const int rg = x & 31;
  const int bb = x >> 5;
  const int n0 = rg * 16;
  const int t = threadIdx.x;
  const int l = t & 63, wid = t >> 6;
  const int q = l >> 4, rl = l & 15;

  const float* e2p = e2 + (size_t)bb * N_;
  for (int i = t; i < N_ / 4; i += 256) ((float4*)e2s)[i] = ((const float4*)e2p)[i];
  __syncthreads();

  const int row = n0 + rl;
  const float e1r = e1[(size_t)bb * N_ + row];
  const u64* mr = maskw + ((size_t)bb * N_ + row) * 8;

  f32x4 acc[6];
  #pragma unroll
  for (int c = 0; c < 6; ++c) acc[c] = (f32x4){0.f, 0.f, 0.f, 0.f};
  const unsigned short* wb = wh2T + (size_t)bb * 96 * 512;
  float dummy;

  #pragma unroll
  for (int tts = 0; tts < 2; ++tts) {
    const int tt = wid * 2 + tts;
    short8 bf[6][2];
    #pragma unroll
    for (int c = 0; c < 6; ++c) {
      const unsigned short* bp = wb + (size_t)(c * 16 + rl) * 512 + tt * 64 + q * 8;
      bf[c][0] = *(const short8*)bp;
      bf[c][1] = *(const short8*)(bp + 32);
    }
    u64 word = mr[tt];
    short8 af0 = build_af(e2s, e1r, word, tt * 64 + q * 8, q * 8, dummy);
    short8 af1 = build_af(e2s, e1r, word, tt * 64 + 32 + q * 8, 32 + q * 8, dummy);
    #pragma unroll
    for (int c = 0; c < 6; ++c) {
      acc[c] = __builtin_amdgcn_mfma_f32_16x16x32_bf16(af0, bf[c][0], acc[c], 0, 0, 0);
      acc[c] = __builtin_amdgcn_mfma_f32_16x16x32_bf16(af1, bf[c][1], acc[c], 0, 0, 0);
    }
  }

  #pragma unroll
  for (int c = 0; c < 6; ++c)
    #pragma unroll
    for (int r = 0; r < 4; ++r) red[wid][l][c * 4 + r] = acc[c][r];
  __syncthreads();

  if (wid == 0) {
    #pragma unroll
    for (int c = 0; c < 6; ++c)
      #pragma unroll
      for (int r = 0; r < 4; ++r)
        acc[c][r] = red[0][l][c * 4 + r] + red[1][l][c * 4 + r] +
                    red[2][l][c * 4 + r] + red[3][l][c * 4 + r];
    const size_t orow0 = (size_t)bb * N_ + n0;
    #pragma unroll
    for (int r = 0; r < 4; ++r) {
      float srow = __shfl(acc[5][r], (q << 4) | 15);  // col 95 = denom
      float invr = srow > 0.f ? 1.f / srow : 0.f;
      const size_t ob = (orow0 + q * 4 + r) * FO_;
      #pragma unroll
      for (int c = 0; c < 5; ++c) out[ob + c * 16 + rl] = acc[c][r] * invr;
    }
  }
}

extern "C" void kernel_launch(void* const* d_in, const int* in_sizes, int n_in,
                              void* d_out, int out_size, void* d_ws, size_t ws_size,
                              hipStream_t stream) {
  const float* h    = (const float*)d_in[0];
  const int*   adj  = (const int*)d_in[1];
  const float* Ws   = (const float*)d_in[2];
  const float* aa   = (const float*)d_in[3];
  const float* Wout = (const float*)d_in[4];
  const float* aout = (const float*)d_in[5];

  char* ws = (char*)d_ws;
  unsigned short* whT  = (unsigned short*)(ws + 0);         // 6,291,456
  float* e1h           = (float*)(ws + 6291456);            //   196,608
  float* e2h           = (float*)(ws + 6488064);            //   196,608
  u64*   mk            = (u64*)  (ws + 6684672);            // 1,048,576
  float* cat           = (float*)(ws + 7733248);            // 9,830,400
  unsigned short* wh2T = (unsigned short*)(ws + 17563648);  // 32*96*512*2 = 3,145,728
  float* e1o           = (float*)(ws + 20709376);           //    65,536
  float* e2o           = (float*)(ws + 20774912);           //    65,536

  hipLaunchKernelGGL(k1_prep, dim3(768), dim3(256), 0, stream, h, Ws, aa, whT, e1h, e2h);
  hipLaunchKernelGGL(k2_mask, dim3(4096), dim3(256), 0, stream, adj, mk);
  hipLaunchKernelGGL(k3_attn1, dim3(768), dim3(256), 0, stream, whT, e1h, e2h, mk, cat);
  hipLaunchKernelGGL(k4_gemm2, dim3(256), dim3(256), 0, stream, cat, Wout, aout, wh2T, e1o, e2o);
  hipLaunchKernelGGL(k5_attn2, dim3(1024), dim3(256), 0, stream, wh2T, e1o, e2o, mk, (float*)d_out);
}

// Round 5
// 93.527 us; speedup vs baseline: 1.1391x; 1.1391x over previous
//
#include <hip/hip_runtime.h>
#include <stdint.h>

typedef unsigned long long u64;
typedef __attribute__((ext_vector_type(8))) short short8;   // 8 x bf16 (4 VGPR)
typedef __attribute__((ext_vector_type(4))) float f32x4;    // MFMA C/D frag

#define B_ 32
#define N_ 512
#define FIN_ 80
#define FH_ 50
#define NH_ 3
#define FO_ 80
#define CAT_ 150
#define KP_ 160   // padded K for layer-2 GEMM
#define NP_ 96    // padded N for layer-2 (80 cols + 15 zero + 1 ones)

__device__ inline unsigned short f2bf(float f) {  // RNE float -> bf16 bits
  unsigned u = __float_as_uint(f);
  u += 0x7fffu + ((u >> 16) & 1u);
  return (unsigned short)(u >> 16);
}

__device__ inline void fma4(float4& a, float s, const float4& w) {
  a.x += s * w.x; a.y += s * w.y; a.z += s * w.z; a.w += s * w.w;
}

// ---------- K1: Wh = h @ Ws[h]; emit e1h/e2h (f32) + whT (bf16 [col64][j512], col63=1)
__global__ __launch_bounds__(256) void k1_prep(const float* __restrict__ h,
                                               const float* __restrict__ Ws,
                                               const float* __restrict__ attn_a,
                                               unsigned short* __restrict__ whT,
                                               float* __restrict__ e1h,
                                               float* __restrict__ e2h) {
  __shared__ __align__(16) float hs[64 * 84];     // stride 84: 2-way banks (free)
  __shared__ __align__(16) float ws[FIN_ * 64];
  __shared__ __align__(16) float a1s[64];
  __shared__ __align__(16) float a2s[64];
  int x = blockIdx.x;
  const int rt = x & 7; x >>= 3;
  const int bb = x & 31; x >>= 5;
  const int hh = x;  // 0..2
  const int n0 = rt * 64;
  const int t = threadIdx.x;

  {
    const float4* src = (const float4*)(h + ((size_t)bb * N_ + n0) * FIN_);
    for (int i = t; i < 64 * 20; i += 256) {
      int row = i / 20, kq = i % 20;
      *(float4*)&hs[row * 84 + kq * 4] = src[row * 20 + kq];
    }
  }
  {
    const float* src = Ws + (size_t)hh * FIN_ * FH_;
    for (int i = t; i < FIN_ * 64; i += 256) {
      int k = i >> 6, c = i & 63;
      ws[i] = (c < FH_) ? src[k * FH_ + c] : 0.0f;
    }
  }
  if (t < 64) {
    a1s[t] = (t < FH_) ? attn_a[hh * 2 * FH_ + t] : 0.0f;
    a2s[t] = (t < FH_) ? attn_a[hh * 2 * FH_ + FH_ + t] : 0.0f;
  }
  __syncthreads();

  const int r = t >> 2, cq = t & 3;
  float4 acc[4];
  for (int i = 0; i < 4; ++i) acc[i] = make_float4(0.f, 0.f, 0.f, 0.f);
  const float4* ws4 = (const float4*)ws;
  #pragma unroll 4
  for (int k = 0; k < FIN_; ++k) {
    float hv = hs[r * 84 + k];
    #pragma unroll
    for (int i = 0; i < 4; ++i) fma4(acc[i], hv, ws4[k * 16 + cq * 4 + i]);
  }
  {
    const float4* a14 = (const float4*)a1s;
    const float4* a24 = (const float4*)a2s;
    float p1 = 0.f, p2 = 0.f;
    #pragma unroll
    for (int i = 0; i < 4; ++i) {
      float4 a1 = a14[cq * 4 + i], a2 = a24[cq * 4 + i], v = acc[i];
      p1 += v.x * a1.x + v.y * a1.y + v.z * a1.z + v.w * a1.w;
      p2 += v.x * a2.x + v.y * a2.y + v.z * a2.z + v.w * a2.w;
    }
    p1 += __shfl_xor(p1, 1); p1 += __shfl_xor(p1, 2);
    p2 += __shfl_xor(p2, 1); p2 += __shfl_xor(p2, 2);
    if (cq == 0) {
      size_t o = ((size_t)hh * B_ + bb) * N_ + n0 + r;
      e1h[o] = p1; e2h[o] = p2;
    }
  }
  __syncthreads();
  float* tb = hs;  // reuse as tb[j][col], 64x64
  {
    float4* trow = (float4*)(tb + r * 64);
    #pragma unroll
    for (int i = 0; i < 4; ++i) trow[cq * 4 + i] = acc[i];
  }
  __syncthreads();
  for (int g = t; g < 512; g += 256) {
    const int col = g >> 3, jg = g & 7;
    unsigned short pk[8];
    #pragma unroll
    for (int e = 0; e < 8; ++e)
      pk[e] = (col == 63) ? (unsigned short)0x3f80 : f2bf(tb[(jg * 8 + e) * 64 + col]);
    uint4 o;
    o.x = (unsigned)pk[0] | ((unsigned)pk[1] << 16);
    o.y = (unsigned)pk[2] | ((unsigned)pk[3] << 16);
    o.z = (unsigned)pk[4] | ((unsigned)pk[5] << 16);
    o.w = (unsigned)pk[6] | ((unsigned)pk[7] << 16);
    *(uint4*)&whT[(((size_t)hh * B_ + bb) * 64 + col) * 512 + n0 + jg * 8] = o;
  }
}

// ---------- K2: adj -> bitmask; block 0 also packs WoutT (bf16) + wv1/wv2 (f32) ---
__global__ __launch_bounds__(256) void k2_mask(const int* __restrict__ adj,
                                               const float* __restrict__ Wout,
                                               const float* __restrict__ a_out,
                                               u64* __restrict__ maskw,
                                               unsigned short* __restrict__ WoutT,
                                               float* __restrict__ wv1,
                                               float* __restrict__ wv2) {
  const int t = threadIdx.x;
  const int w = t >> 6, l = t & 63;
  const int row = blockIdx.x * 4 + w;
  const int* src = adj + (size_t)row * N_;
  u64* dst = maskw + (size_t)row * 8;
  #pragma unroll
  for (int it = 0; it < 8; ++it) {
    int v = src[it * 64 + l];
    u64 m = __ballot(v != 0);
    if (l == 0) dst[it] = m;
  }
  if (blockIdx.x == 0) {
    // WoutT[col 96][k 160] bf16, transposed+padded (zeros outside 80x150)
    for (int i = t; i < NP_ * KP_ / 4; i += 256) {
      int base = i * 4;
      int col = base / KP_, k0 = base % KP_;
      unsigned short pk[4];
      #pragma unroll
      for (int e = 0; e < 4; ++e) {
        int k = k0 + e;
        pk[e] = (col < FO_ && k < CAT_) ? f2bf(Wout[(size_t)k * FO_ + col]) : 0;
      }
      uint2 o;
      o.x = (unsigned)pk[0] | ((unsigned)pk[1] << 16);
      o.y = (unsigned)pk[2] | ((unsigned)pk[3] << 16);
      ((uint2*)WoutT)[i] = o;
    }
    // wv1/wv2[k] = sum_c Wout[k][c] * a_out[(0|80)+c]   (f32-exact e-path)
    for (int k = t; k < CAT_; k += 256) {
      const float4* wr = (const float4*)(Wout + (size_t)k * FO_);
      const float4* a1 = (const float4*)a_out;
      const float4* a2 = (const float4*)(a_out + FO_);
      float p1 = 0.f, p2 = 0.f;
      #pragma unroll
      for (int i = 0; i < 20; ++i) {
        float4 v = wr[i], x1 = a1[i], x2 = a2[i];
        p1 += v.x * x1.x + v.y * x1.y + v.z * x1.z + v.w * x1.w;
        p2 += v.x * x2.x + v.y * x2.y + v.z * x2.z + v.w * x2.w;
      }
      wv1[k] = p1; wv2[k] = p2;
    }
  }
}

// A-fragment builder: p = exp(min(lrelu(e1+e2),60)) masked, bf16 -------------------
__device__ inline short8 build_af(const float* e2s, float e1r, u64 word,
                                  int jb, int shift) {
  short8 af;
  unsigned b0 = (unsigned)(word >> shift) & 0xffu;
  float4 va = *(const float4*)&e2s[jb];
  float4 vb = *(const float4*)&e2s[jb + 4];
  float ev[8] = {va.x, va.y, va.z, va.w, vb.x, vb.y, vb.z, vb.w};
  #pragma unroll
  for (int e = 0; e < 8; ++e) {
    float sv = e1r + ev[e];
    sv = fmaxf(sv, 0.2f * sv);
    sv = fminf(sv, 60.f);
    float arg = ((b0 >> e) & 1u) ? sv : -1e30f;
    af[e] = (short)f2bf(__expf(arg));
  }
  return af;
}

// ---------- K3: layer-1 attention -> catbf (bf16 [row][160]) + per-head e-partials -
__global__ __launch_bounds__(256) void k3_attn1(const unsigned short* __restrict__ whT,
                                                const float* __restrict__ e1,
                                                const float* __restrict__ e2,
                                                const u64* __restrict__ maskw,
                                                const float* __restrict__ wv1,
                                                const float* __restrict__ wv2,
                                                unsigned short* __restrict__ catbf,
                                                float* __restrict__ e1p,
                                                float* __restrict__ e2p) {
  __shared__ __align__(16) float e2s[N_];
  int x = (int)((blockIdx.x & 7) * 96 + (blockIdx.x >> 3));  // XCD-bijective
  const int rt = x & 7; x >>= 3;
  const int bb = x & 31; x >>= 5;
  const int hh = x;
  const int n0 = rt * 64;
  const int t = threadIdx.x;
  const int l = t & 63, wid = t >> 6;
  const int q = l >> 4, rl = l & 15;

  const float* e2pp = e2 + ((size_t)hh * B_ + bb) * N_;
  for (int i = t; i < N_ / 4; i += 256) ((float4*)e2s)[i] = ((const float4*)e2pp)[i];
  __syncthreads();

  const int row = n0 + wid * 16 + rl;
  const float e1r = e1[((size_t)hh * B_ + bb) * N_ + row];
  const u64* mr = maskw + ((size_t)bb * N_ + row) * 8;

  f32x4 acc[4];
  #pragma unroll
  for (int c = 0; c < 4; ++c) acc[c] = (f32x4){0.f, 0.f, 0.f, 0.f};
  const unsigned short* wb = whT + ((size_t)hh * B_ + bb) * 64 * 512;

  for (int tt = 0; tt < 8; ++tt) {
    short8 bf[4][2];
    #pragma unroll
    for (int c = 0; c < 4; ++c) {
      const unsigned short* bp = wb + (size_t)(c * 16 + rl) * 512 + tt * 64 + q * 8;
      bf[c][0] = *(const short8*)bp;
      bf[c][1] = *(const short8*)(bp + 32);
    }
    u64 word = mr[tt];
    short8 af0 = build_af(e2s, e1r, word, tt * 64 + q * 8, q * 8);
    short8 af1 = build_af(e2s, e1r, word, tt * 64 + 32 + q * 8, 32 + q * 8);
    #pragma unroll
    for (int c = 0; c < 4; ++c) {
      acc[c] = __builtin_amdgcn_mfma_f32_16x16x32_bf16(af0, bf[c][0], acc[c], 0, 0, 0);
      acc[c] = __builtin_amdgcn_mfma_f32_16x16x32_bf16(af1, bf[c][1], acc[c], 0, 0, 0);
    }
  }

  // wv gather for this lane's columns (col = c*16+rl, guard col<50)
  float w1c[4], w2c[4];
  #pragma unroll
  for (int c = 0; c < 4; ++c) {
    const int col = c * 16 + rl;
    w1c[c] = (col < FH_) ? wv1[hh * FH_ + col] : 0.f;
    w2c[c] = (col < FH_) ? wv2[hh * FH_ + col] : 0.f;
  }

  const size_t orow0 = (size_t)bb * N_ + n0 + wid * 16;
  #pragma unroll
  for (int r = 0; r < 4; ++r) {
    float srow = __shfl(acc[3][r], (q << 4) | 15);  // col 63 = denom (ones col)
    float invr = srow > 0.f ? 1.f / srow : 0.f;
    const size_t grow = orow0 + q * 4 + r;
    float p1 = 0.f, p2 = 0.f;
    #pragma unroll
    for (int c = 0; c < 4; ++c) {
      const int col = c * 16 + rl;
      if (col < FH_) {
        float v = acc[c][r] * invr;
        v = v > 0.f ? v : __expf(v) - 1.f;  // ELU
        catbf[grow * KP_ + hh * FH_ + col] = f2bf(v);
        p1 += v * w1c[c];
        p2 += v * w2c[c];
      }
    }
    // reduce within the 16-lane q-group (rows are per-(q,r))
    p1 += __shfl_xor(p1, 1); p1 += __shfl_xor(p1, 2);
    p1 += __shfl_xor(p1, 4); p1 += __shfl_xor(p1, 8);
    p2 += __shfl_xor(p2, 1); p2 += __shfl_xor(p2, 2);
    p2 += __shfl_xor(p2, 4); p2 += __shfl_xor(p2, 8);
    if (rl == 0) {
      e1p[(size_t)hh * (B_ * N_) + grow] = p1;
      e2p[(size_t)hh * (B_ * N_) + grow] = p2;
    }
  }
  // zero-pad K columns 150..159 (ws is poisoned): hh==2 blocks own it
  if (hh == 2 && t < 64) {
    const size_t grow = (size_t)bb * N_ + n0 + t;
    unsigned* zp = (unsigned*)&catbf[grow * KP_ + CAT_];
    #pragma unroll
    for (int i = 0; i < 5; ++i) zp[i] = 0u;
  }
}

// ---------- K4: Wh2 = catbf @ WoutT via MFMA -> wh2T bf16 [bb][96][512] -----------
// MFMA writes cols 0..79 ONLY (nt<5); fill section exclusively owns cols 80..95.
__global__ __launch_bounds__(256) void k4_gemm2(const unsigned short* __restrict__ catbf,
                                                const unsigned short* __restrict__ WoutT,
                                                unsigned short* __restrict__ wh2T) {
  const int t = threadIdx.x, l = t & 63, wid = t >> 6;
  const int q = l >> 4, rl = l & 15;
  const int blk = blockIdx.x;            // 256 blocks x 64 rows
  const int jbase = blk * 64 + wid * 16;
  f32x4 acc[5];
  #pragma unroll
  for (int nt = 0; nt < 5; ++nt) acc[nt] = (f32x4){0.f, 0.f, 0.f, 0.f};
  const unsigned short* ap = catbf + (size_t)(jbase + rl) * KP_ + q * 8;
  #pragma unroll
  for (int kk = 0; kk < 5; ++kk) {
    short8 a = *(const short8*)(ap + kk * 32);
    #pragma unroll
    for (int nt = 0; nt < 5; ++nt) {
      short8 b = *(const short8*)&WoutT[(size_t)(nt * 16 + rl) * KP_ + kk * 32 + q * 8];
      acc[nt] = __builtin_amdgcn_mfma_f32_16x16x32_bf16(a, b, acc[nt], 0, 0, 0);
    }
  }
  const int bb = blk >> 3, jt = blk & 7;
  const int j0 = jt * 64 + wid * 16 + q * 4;
  #pragma unroll
  for (int nt = 0; nt < 5; ++nt) {
    const int col = nt * 16 + rl;
    unsigned short pk[4];
    #pragma unroll
    for (int r = 0; r < 4; ++r) pk[r] = f2bf(acc[nt][r]);
    uint2 o;
    o.x = (unsigned)pk[0] | ((unsigned)pk[1] << 16);
    o.y = (unsigned)pk[2] | ((unsigned)pk[3] << 16);
    *(uint2*)&wh2T[((size_t)bb * NP_ + col) * 512 + j0] = o;
  }
  {  // cols 80..94 zero, col 95 ones (softmax denominator) — disjoint from MFMA write
    const int col = 80 + (t >> 4), jq = (t & 15) * 4;
    unsigned fill = (col == 95) ? 0x3f803f80u : 0u;
    uint2 o; o.x = fill; o.y = fill;
    *(uint2*)&wh2T[((size_t)bb * NP_ + col) * 512 + jt * 64 + jq] = o;
  }
}

// ---------- K5: layer-2 attention, j-split. 16 rows/block, 4 waves over j ---------
__global__ __launch_bounds__(256) void k5_attn2(const unsigned short* __restrict__ wh2T,
                                                const float* __restrict__ e1p,
                                                const float* __restrict__ e2p,
                                                const u64* __restrict__ maskw,
                                                float* __restrict__ out) {
  __shared__ __align__(16) float e2s[N_];
  __shared__ __align__(16) float red[4][64][25];  // stride 25: conflict-free
  int x = (int)((blockIdx.x & 7) * 128 + (blockIdx.x >> 3));  // XCD-bijective
  const int rg = x & 31;
  const int bb = x >> 5;
  const int n0 = rg * 16;
  const int t = threadIdx.x;
  const int l = t & 63, wid = t >> 6;
  const int q = l >> 4, rl = l & 15;

  for (int i = t; i < N_ / 4; i += 256) {
    float4 v0 = ((const float4*)(e2p))[(size_t)bb * 128 + i];
    float4 v1 = ((const float4*)(e2p + B_ * N_))[(size_t)bb * 128 + i];
    float4 v2 = ((const float4*)(e2p + 2 * B_ * N_))[(size_t)bb * 128 + i];
    float4 s;
    s.x = v0.x + v1.x + v2.x; s.y = v0.y + v1.y + v2.y;
    s.z = v0.z + v1.z + v2.z; s.w = v0.w + v1.w + v2.w;
    ((float4*)e2s)[i] = s;
  }
  __syncthreads();

  const int row = n0 + rl;
  const size_t gr = (size_t)bb * N_ + row;
  const float e1r = e1p[gr] + e1p[B_ * N_ + gr] + e1p[2 * B_ * N_ + gr];
  const u64* mr = maskw + gr * 8;

  f32x4 acc[6];
  #pragma unroll
  for (int c = 0; c < 6; ++c) acc[c] = (f32x4){0.f, 0.f, 0.f, 0.f};
  const unsigned short* wb = wh2T + (size_t)bb * NP_ * 512;

  #pragma unroll
  for (int tts = 0; tts < 2; ++tts) {
    const int tt = wid * 2 + tts;
    short8 bf[6][2];
    #pragma unroll
    for (int c = 0; c < 6; ++c) {
      const unsigned short* bp = wb + (size_t)(c * 16 + rl) * 512 + tt * 64 + q * 8;
      bf[c][0] = *(const short8*)bp;
      bf[c][1] = *(const short8*)(bp + 32);
    }
    u64 word = mr[tt];
    short8 af0 = build_af(e2s, e1r, word, tt * 64 + q * 8, q * 8);
    short8 af1 = build_af(e2s, e1r, word, tt * 64 + 32 + q * 8, 32 + q * 8);
    #pragma unroll
    for (int c = 0; c < 6; ++c) {
      acc[c] = __builtin_amdgcn_mfma_f32_16x16x32_bf16(af0, bf[c][0], acc[c], 0, 0, 0);
      acc[c] = __builtin_amdgcn_mfma_f32_16x16x32_bf16(af1, bf[c][1], acc[c], 0, 0, 0);
    }
  }

  #pragma unroll
  for (int c = 0; c < 6; ++c)
    #pragma unroll
    for (int r = 0; r < 4; ++r) red[wid][l][c * 4 + r] = acc[c][r];
  __syncthreads();

  if (wid == 0) {
    #pragma unroll
    for (int c = 0; c < 6; ++c)
      #pragma unroll
      for (int r = 0; r < 4; ++r)
        acc[c][r] = red[0][l][c * 4 + r] + red[1][l][c * 4 + r] +
                    red[2][l][c * 4 + r] + red[3][l][c * 4 + r];
    const size_t orow0 = (size_t)bb * N_ + n0;
    #pragma unroll
    for (int r = 0; r < 4; ++r) {
      float srow = __shfl(acc[5][r], (q << 4) | 15);  // col 95 = denom
      float invr = srow > 0.f ? 1.f / srow : 0.f;
      const size_t ob = (orow0 + q * 4 + r) * FO_;
      #pragma unroll
      for (int c = 0; c < 5; ++c) out[ob + c * 16 + rl] = acc[c][r] * invr;
    }
  }
}

extern "C" void kernel_launch(void* const* d_in, const int* in_sizes, int n_in,
                              void* d_out, int out_size, void* d_ws, size_t ws_size,
                              hipStream_t stream) {
  const float* h    = (const float*)d_in[0];
  const int*   adj  = (const int*)d_in[1];
  const float* Ws   = (const float*)d_in[2];
  const float* aa   = (const float*)d_in[3];
  const float* Wout = (const float*)d_in[4];
  const float* aout = (const float*)d_in[5];

  char* ws = (char*)d_ws;
  unsigned short* whT   = (unsigned short*)(ws + 0);         // 6,291,456
  float* e1h            = (float*)(ws + 6291456);            //   196,608
  float* e2h            = (float*)(ws + 6488064);            //   196,608
  u64*   mk             = (u64*)  (ws + 6684672);            // 1,048,576
  unsigned short* catbf = (unsigned short*)(ws + 7733248);   // 16384*160*2 = 5,242,880
  unsigned short* WoutT = (unsigned short*)(ws + 12976128);  //    30,720 (+pad)
  float* wv1            = (float*)(ws + 13008896);           //       600 (+pad)
  float* wv2            = (float*)(ws + 13009920);           //       600 (+pad)
  float* e1p            = (float*)(ws + 13010944);           // 3*16384*4 = 196,608
  float* e2p            = (float*)(ws + 13207552);           //   196,608
  unsigned short* wh2T  = (unsigned short*)(ws + 13404160);  // 32*96*512*2 = 3,145,728

  hipLaunchKernelGGL(k1_prep, dim3(768), dim3(256), 0, stream, h, Ws, aa, whT, e1h, e2h);
  hipLaunchKernelGGL(k2_mask, dim3(4096), dim3(256), 0, stream, adj, Wout, aout, mk,
                     WoutT, wv1, wv2);
  hipLaunchKernelGGL(k3_attn1, dim3(768), dim3(256), 0, stream, whT, e1h, e2h, mk,
                     wv1, wv2, catbf, e1p, e2p);
  hipLaunchKernelGGL(k4_gemm2, dim3(256), dim3(256), 0, stream, catbf, WoutT, wh2T);
  hipLaunchKernelGGL(k5_attn2, dim3(1024), dim3(256), 0, stream, wh2T, e1p, e2p, mk,
                     (float*)d_out);
}